// Round 5
// baseline (330.166 us; speedup 1.0000x reference)
//
#include <hip/hip_runtime.h>

#define BN_EPS 1e-5f
typedef unsigned short u16;
typedef unsigned int u32;

// ws layout: stats = 72 floats at ws (sum1[28], ssq1[28], sum2[8], ssq2[8])
//   Psrc at ws+1024B : N*32 u16 (bf16, row stride 32, 28 used)   3.2 MB
//   Pdst next        : N*32 u16                                   3.2 MB
//   y1   next        : E*32 u16 (bf16, row stride 32, 28 used)   38.4 MB
//   y2   next        : E*8  u16 (bf16)                            9.6 MB

__device__ __forceinline__ u16 f2bf(float f) {
  u32 u = __float_as_uint(f);
  return (u16)((u + 0x7fffu + ((u >> 16) & 1u)) >> 16);  // RNE
}
__device__ __forceinline__ float bf2f(u16 s) {
  return __uint_as_float(((u32)s) << 16);
}
__device__ __forceinline__ u32 pack2(float a, float b) {
  return (u32)f2bf(a) | ((u32)f2bf(b) << 16);
}

// K1: per-node projection (proven). bf16 rows padded to 64B. Zeroes stats[0..72).
__global__ void k1_proj(const float* __restrict__ h, const float* __restrict__ W1,
                        u16* __restrict__ Psrc, u16* __restrict__ Pdst,
                        float* __restrict__ stats, int N) {
  if (blockIdx.x == 0 && threadIdx.x < 72) stats[threadIdx.x] = 0.f;
  const int half = blockIdx.x & 1;
  const int node = (blockIdx.x >> 1) * 256 + threadIdx.x;
  if (node >= N) return;
  const float* __restrict__ wbase = W1 + half * 128;
  const float4* __restrict__ h4 = (const float4*)(h + (size_t)node * 128);
  float acc[28];
#pragma unroll
  for (int c = 0; c < 28; c++) acc[c] = 0.f;
  for (int kk = 0; kk < 16; kk++) {
    const float4 a = h4[kk * 2];
    const float4 b = h4[kk * 2 + 1];
#pragma unroll
    for (int c = 0; c < 28; c++) {
      const float* w = wbase + c * 268 + kk * 8;  // wave-uniform -> s_load
      acc[c] += a.x * w[0] + a.y * w[1] + a.z * w[2] + a.w * w[3]
              + b.x * w[4] + b.y * w[5] + b.z * w[6] + b.w * w[7];
    }
  }
  u16* outp = (half == 0 ? Psrc : Pdst) + (size_t)node * 32;
  u32 u[14];
#pragma unroll
  for (int j = 0; j < 14; j++) u[j] = pack2(acc[2 * j], acc[2 * j + 1]);
  uint4* p4 = (uint4*)outp;
  p4[0] = make_uint4(u[0], u[1], u[2], u[3]);
  p4[1] = make_uint4(u[4], u[5], u[6], u[7]);
  p4[2] = make_uint4(u[8], u[9], u[10], u[11]);
  *(uint2*)((u32*)outp + 12) = make_uint2(u[12], u[13]);
}

// K2 v3: wave-per-edge. Wave index forced scalar -> src/dst/ef via s_load.
// Lanes 0..27 compute ef-dot + Psrc gather; lanes 32..59 gather Pdst; cross-half
// add via shfl_xor(32). Unroll-4 batches keep 8 gathers in flight.
__global__ void __launch_bounds__(256) k2_l1(
    const u16* __restrict__ Psrc, const u16* __restrict__ Pdst,
    const float* __restrict__ ef,
    const int* __restrict__ src, const int* __restrict__ dst,
    const float* __restrict__ W1, const float* __restrict__ b1,
    u16* __restrict__ y1, float* __restrict__ stats, int E, int epw) {
  const int tid = threadIdx.x;
  const int lane = tid & 63;
  const int c = lane & 31;
  const int wv = __builtin_amdgcn_readfirstlane(tid >> 6);  // scalar wave idx 0..3
  const int wid = blockIdx.x * 4 + wv;
  int e0 = wid * epw;
  int e1 = e0 + epw;
  if (e1 > E) e1 = E;
  if (e0 > e1) e0 = e1;

  const bool isA = (lane < 28);
  float w[12];
#pragma unroll
  for (int j = 0; j < 12; j++) w[j] = 0.f;
  float bias = 0.f;
  if (isA) {
    const float4* wp = (const float4*)(W1 + lane * 268 + 256);
    float4 w0 = wp[0], w1 = wp[1], w2 = wp[2];
    w[0] = w0.x; w[1] = w0.y; w[2] = w0.z; w[3] = w0.w;
    w[4] = w1.x; w[5] = w1.y; w[6] = w1.z; w[7] = w1.w;
    w[8] = w2.x; w[9] = w2.y; w[10] = w2.z; w[11] = w2.w;
    bias = b1[lane];
  }

  float sum = 0.f, ssq = 0.f;
  int e = e0;
  for (; e + 4 <= e1; e += 4) {
    int sI[4], dI[4];
#pragma unroll
    for (int k = 0; k < 4; k++) { sI[k] = src[e + k]; dI[k] = dst[e + k]; }
    float efv[4][12];
#pragma unroll
    for (int k = 0; k < 4; k++) {
      const float* er = ef + (size_t)(e + k) * 12;  // uniform -> s_load
#pragma unroll
      for (int j = 0; j < 12; j++) efv[k][j] = er[j];
    }
    float p[4];
    if (lane < 32) {
#pragma unroll
      for (int k = 0; k < 4; k++) p[k] = bf2f(Psrc[(size_t)(u32)sI[k] * 32 + c]);
    } else {
#pragma unroll
      for (int k = 0; k < 4; k++) p[k] = bf2f(Pdst[(size_t)(u32)dI[k] * 32 + c]);
    }
#pragma unroll
    for (int k = 0; k < 4; k++) {
      float part = bias;
#pragma unroll
      for (int j = 0; j < 12; j++) part = fmaf(efv[k][j], w[j], part);
      part += p[k];
      const float y = part + __shfl_xor(part, 32);
      if (isA) {
        sum += y;
        ssq += y * y;
        __builtin_nontemporal_store(f2bf(y), &y1[(size_t)(e + k) * 32 + (u32)lane]);
      }
    }
  }
  for (; e < e1; e++) {
    const int sI = src[e], dI = dst[e];
    float efv[12];
    const float* er = ef + (size_t)e * 12;
#pragma unroll
    for (int j = 0; j < 12; j++) efv[j] = er[j];
    float p;
    if (lane < 32) p = bf2f(Psrc[(size_t)(u32)sI * 32 + c]);
    else           p = bf2f(Pdst[(size_t)(u32)dI * 32 + c]);
    float part = bias;
#pragma unroll
    for (int j = 0; j < 12; j++) part = fmaf(efv[j], w[j], part);
    part += p;
    const float y = part + __shfl_xor(part, 32);
    if (isA) {
      sum += y;
      ssq += y * y;
      __builtin_nontemporal_store(f2bf(y), &y1[(size_t)e * 32 + (u32)lane]);
    }
  }

  __shared__ float red[2][4][28];
  if (lane < 28) { red[0][wv][lane] = sum; red[1][wv][lane] = ssq; }
  __syncthreads();
  if (tid < 28) {
    atomicAdd(&stats[tid], red[0][0][tid] + red[0][1][tid] + red[0][2][tid] + red[0][3][tid]);
    atomicAdd(&stats[28 + tid], red[1][0][tid] + red[1][1][tid] + red[1][2][tid] + red[1][3][tid]);
  }
}

// K4 v2: LDS-staged tiles. Block stages 256 y1 rows (16KB) via coalesced nt
// dword loads into LDS (row stride 17 words -> conflict-free reads), then
// thread t computes edge T+t. BN1 coefs folded per-thread.
__global__ void __launch_bounds__(256) k4_l2(
    const u32* __restrict__ y1w, const float* __restrict__ stats,
    const float* __restrict__ g1, const float* __restrict__ be1,
    const float* __restrict__ W2, const float* __restrict__ b2,
    u16* __restrict__ y2, float* __restrict__ stats2, int E, float invE) {
  __shared__ u32 tile[256 * 17];
  float sc[28], sh[28];
#pragma unroll
  for (int cc = 0; cc < 28; cc++) {
    const float m = stats[cc] * invE;
    const float v = stats[28 + cc] * invE - m * m;
    const float s = g1[cc] * rsqrtf(v + BN_EPS);
    sc[cc] = s; sh[cc] = be1[cc] - m * s;
  }
  float as[8], aq[8];
#pragma unroll
  for (int o = 0; o < 8; o++) { as[o] = 0.f; aq[o] = 0.f; }
  const int tid = threadIdx.x;
  for (int T = blockIdx.x * 256; T < E; T += gridDim.x * 256) {
    int cnt = E - T; if (cnt > 256) cnt = 256;
    __syncthreads();
    const int total = cnt * 16;
    for (int i = tid; i < total; i += 256) {
      tile[(i >> 4) * 17 + (i & 15)] =
          __builtin_nontemporal_load(&y1w[(size_t)T * 16 + i]);
    }
    __syncthreads();
    if (tid < cnt) {
      u32 uu[14];
#pragma unroll
      for (int i = 0; i < 14; i++) uu[i] = tile[tid * 17 + i];
      float acc[8];
#pragma unroll
      for (int o = 0; o < 8; o++) acc[o] = b2[o];
#pragma unroll
      for (int k = 0; k < 14; k++) {
        const float fe = __uint_as_float(uu[k] << 16);
        const float fo = __uint_as_float(uu[k] & 0xffff0000u);
        const float se = fmaxf(fmaf(fe, sc[2 * k], sh[2 * k]), 0.f);
        const float so = fmaxf(fmaf(fo, sc[2 * k + 1], sh[2 * k + 1]), 0.f);
#pragma unroll
        for (int o = 0; o < 8; o++) {
          acc[o] = fmaf(W2[o * 28 + 2 * k], se, acc[o]);      // uniform -> s_load
          acc[o] = fmaf(W2[o * 28 + 2 * k + 1], so, acc[o]);
        }
      }
      *(uint4*)(y2 + (size_t)(T + tid) * 8) =
          make_uint4(pack2(acc[0], acc[1]), pack2(acc[2], acc[3]),
                     pack2(acc[4], acc[5]), pack2(acc[6], acc[7]));
#pragma unroll
      for (int o = 0; o < 8; o++) { as[o] += acc[o]; aq[o] += acc[o] * acc[o]; }
    }
  }
#pragma unroll
  for (int o = 0; o < 8; o++) {
    for (int off = 32; off; off >>= 1) {
      as[o] += __shfl_down(as[o], off);
      aq[o] += __shfl_down(aq[o], off);
    }
  }
  __shared__ float redS[4][16];
  const int wave = tid >> 6, lane = tid & 63;
  if (lane == 0) {
#pragma unroll
    for (int o = 0; o < 8; o++) { redS[wave][o] = as[o]; redS[wave][8 + o] = aq[o]; }
  }
  __syncthreads();
  if (tid < 16) {
    atomicAdd(&stats2[tid], redS[0][tid] + redS[1][tid] + redS[2][tid] + redS[3][tid]);
  }
}

// K6: BN2 coefs per-thread, out = relu(BN2(y2)) @ W3.T + b3
__global__ void k6_l3(const u16* __restrict__ y2, const float* __restrict__ stats,
                      const float* __restrict__ g2, const float* __restrict__ be2,
                      const float* __restrict__ W3, const float* __restrict__ b3,
                      float* __restrict__ out, int E, float invE) {
  float sc[8], sh[8], w3[8];
#pragma unroll
  for (int o = 0; o < 8; o++) {
    const float m = stats[56 + o] * invE;
    const float v = stats[64 + o] * invE - m * m;
    const float s = g2[o] * rsqrtf(v + BN_EPS);
    sc[o] = s; sh[o] = be2[o] - m * s; w3[o] = W3[o];
  }
  const int e = blockIdx.x * blockDim.x + threadIdx.x;
  if (e >= E) return;
  const uint4 r = *(const uint4*)(y2 + (size_t)e * 8);
  u32 uu[4] = {r.x, r.y, r.z, r.w};
  float acc = b3[0];
#pragma unroll
  for (int k = 0; k < 4; k++) {
    const float fe = __uint_as_float(uu[k] << 16);
    const float fo = __uint_as_float(uu[k] & 0xffff0000u);
    acc = fmaf(w3[2 * k], fmaxf(fmaf(fe, sc[2 * k], sh[2 * k]), 0.f), acc);
    acc = fmaf(w3[2 * k + 1], fmaxf(fmaf(fo, sc[2 * k + 1], sh[2 * k + 1]), 0.f), acc);
  }
  out[e] = acc;
}

extern "C" void kernel_launch(void* const* d_in, const int* in_sizes, int n_in,
                              void* d_out, int out_size, void* d_ws, size_t ws_size,
                              hipStream_t stream) {
  const float* h   = (const float*)d_in[0];
  const float* ef  = (const float*)d_in[1];
  const int* src   = (const int*)d_in[2];
  const int* dst   = (const int*)d_in[3];
  const float* W1  = (const float*)d_in[4];
  const float* b1  = (const float*)d_in[5];
  const float* g1  = (const float*)d_in[6];
  const float* be1 = (const float*)d_in[7];
  const float* W2  = (const float*)d_in[8];
  const float* b2  = (const float*)d_in[9];
  const float* g2  = (const float*)d_in[10];
  const float* be2 = (const float*)d_in[11];
  const float* W3  = (const float*)d_in[12];
  const float* b3  = (const float*)d_in[13];
  float* out = (float*)d_out;

  const int N = in_sizes[0] / 128;
  const int E = in_sizes[2];
  const float invE = 1.0f / (float)E;

  char* ws = (char*)d_ws;
  float* stats = (float*)ws;                       // 72 floats
  u16* Psrc = (u16*)(ws + 1024);
  u16* Pdst = Psrc + (size_t)N * 32;
  u16* y1   = Pdst + (size_t)N * 32;
  u16* y2   = y1 + (size_t)E * 32;

  const int nodeBlocks = (N + 255) / 256;
  k1_proj<<<nodeBlocks * 2, 256, 0, stream>>>(h, W1, Psrc, Pdst, stats, N);

  const int K2B = 2560;                            // 10240 waves
  const int epw = (E + K2B * 4 - 1) / (K2B * 4);   // edges per wave
  k2_l1<<<K2B, 256, 0, stream>>>(Psrc, Pdst, ef, src, dst, W1, b1, y1, stats, E, epw);

  const int K4B = (E + 255) / 256;
  k4_l2<<<K4B, 256, 0, stream>>>((const u32*)y1, stats, g1, be1, W2, b2, y2,
                                 stats + 56, E, invE);
  k6_l3<<<(E + 255) / 256, 256, 0, stream>>>(y2, stats, g2, be2, W3, b3, out, E, invE);
}

// Round 6
// 304.202 us; speedup vs baseline: 1.0853x; 1.0853x over previous
//
#include <hip/hip_runtime.h>

#define BN_EPS 1e-5f
typedef unsigned short u16;
typedef unsigned int u32;

// ws layout: stats = 72 floats at ws (sum1[28], ssq1[28], sum2[8], ssq2[8])
//   Psrc at ws+1024B : N*32 u16 (bf16, row stride 32 = 64B, 28 used)  3.2 MB
//   Pdst next        : N*32 u16                                        3.2 MB
//   y1   next        : E*28 u16 (bf16, PACKED 56B rows)               33.6 MB
//   y2   next        : E*8  u16 (bf16)                                 9.6 MB

__device__ __forceinline__ u16 f2bf(float f) {
  u32 u = __float_as_uint(f);
  return (u16)((u + 0x7fffu + ((u >> 16) & 1u)) >> 16);  // RNE
}
__device__ __forceinline__ float bf2f(u16 s) {
  return __uint_as_float(((u32)s) << 16);
}
__device__ __forceinline__ u32 pack2(float a, float b) {
  return (u32)f2bf(a) | ((u32)f2bf(b) << 16);
}

// K1: per-node projection (proven). bf16 rows padded to 64B. Zeroes stats[0..72).
__global__ void k1_proj(const float* __restrict__ h, const float* __restrict__ W1,
                        u16* __restrict__ Psrc, u16* __restrict__ Pdst,
                        float* __restrict__ stats, int N) {
  if (blockIdx.x == 0 && threadIdx.x < 72) stats[threadIdx.x] = 0.f;
  const int half = blockIdx.x & 1;
  const int node = (blockIdx.x >> 1) * 256 + threadIdx.x;
  if (node >= N) return;
  const float* __restrict__ wbase = W1 + half * 128;
  const float4* __restrict__ h4 = (const float4*)(h + (size_t)node * 128);
  float acc[28];
#pragma unroll
  for (int c = 0; c < 28; c++) acc[c] = 0.f;
  for (int kk = 0; kk < 16; kk++) {
    const float4 a = h4[kk * 2];
    const float4 b = h4[kk * 2 + 1];
#pragma unroll
    for (int c = 0; c < 28; c++) {
      const float* w = wbase + c * 268 + kk * 8;  // wave-uniform -> s_load
      acc[c] += a.x * w[0] + a.y * w[1] + a.z * w[2] + a.w * w[3]
              + b.x * w[4] + b.y * w[5] + b.z * w[6] + b.w * w[7];
    }
  }
  u16* outp = (half == 0 ? Psrc : Pdst) + (size_t)node * 32;
  u32 u[14];
#pragma unroll
  for (int j = 0; j < 14; j++) u[j] = pack2(acc[2 * j], acc[2 * j + 1]);
  uint4* p4 = (uint4*)outp;
  p4[0] = make_uint4(u[0], u[1], u[2], u[3]);
  p4[1] = make_uint4(u[4], u[5], u[6], u[7]);
  p4[2] = make_uint4(u[8], u[9], u[10], u[11]);
  *(uint2*)((u32*)outp + 12) = make_uint2(u[12], u[13]);
}

// K2 v5: half-wave-per-edge (R2-proven shape: c = lane&31 owns channel c, no
// divergence, no shfl in loop). Unroll-4: int4 index loads + 8 single-line
// gathers in flight. y1 bf16 packed 56B rows -> dense full-line writes.
__global__ void __launch_bounds__(256) k2_l1(
    const u16* __restrict__ Psrc, const u16* __restrict__ Pdst,
    const float* __restrict__ ef,
    const int* __restrict__ src, const int* __restrict__ dst,
    const float* __restrict__ W1, const float* __restrict__ b1,
    u16* __restrict__ y1, float* __restrict__ stats, int E, int epw) {
  const int tid = threadIdx.x;
  const int lane = tid & 63;
  const int c = lane & 31;
  const int g = tid >> 5;                 // half-wave group in block, 0..7
  const int G = blockIdx.x * 8 + g;
  int e0 = G * epw;                       // epw multiple of 8 -> e0 16B-aligned
  int e1 = e0 + epw;
  if (e1 > E) e1 = E;
  if (e0 > e1) e0 = e1;

  const bool act = (c < 28);
  float w[12];
#pragma unroll
  for (int j = 0; j < 12; j++) w[j] = 0.f;
  float bias = 0.f;
  if (act) {
    const float4* wp = (const float4*)(W1 + c * 268 + 256);  // 16B aligned
    float4 w0 = wp[0], w1 = wp[1], w2 = wp[2];
    w[0] = w0.x; w[1] = w0.y; w[2] = w0.z; w[3] = w0.w;
    w[4] = w1.x; w[5] = w1.y; w[6] = w1.z; w[7] = w1.w;
    w[8] = w2.x; w[9] = w2.y; w[10] = w2.z; w[11] = w2.w;
    bias = b1[c];
  }

  float sum = 0.f, ssq = 0.f;
  int e = e0;
  for (; e + 4 <= e1; e += 4) {
    const int4 sI = *(const int4*)(src + e);   // 2 lines/instr (two halves)
    const int4 dI = *(const int4*)(dst + e);
    float pa[4], pb[4];
    pa[0] = bf2f(Psrc[(size_t)(u32)sI.x * 32 + c]);   // 1 line per half-wave
    pa[1] = bf2f(Psrc[(size_t)(u32)sI.y * 32 + c]);
    pa[2] = bf2f(Psrc[(size_t)(u32)sI.z * 32 + c]);
    pa[3] = bf2f(Psrc[(size_t)(u32)sI.w * 32 + c]);
    pb[0] = bf2f(Pdst[(size_t)(u32)dI.x * 32 + c]);
    pb[1] = bf2f(Pdst[(size_t)(u32)dI.y * 32 + c]);
    pb[2] = bf2f(Pdst[(size_t)(u32)dI.z * 32 + c]);
    pb[3] = bf2f(Pdst[(size_t)(u32)dI.w * 32 + c]);
    float4 f0[4], f1[4], f2[4];
#pragma unroll
    for (int k = 0; k < 4; k++) {
      const float4* e4 = (const float4*)(ef + (size_t)(e + k) * 12);  // broadcast
      f0[k] = e4[0]; f1[k] = e4[1]; f2[k] = e4[2];
    }
#pragma unroll
    for (int k = 0; k < 4; k++) {
      float y = bias;
      y = fmaf(f0[k].x, w[0], y); y = fmaf(f0[k].y, w[1], y);
      y = fmaf(f0[k].z, w[2], y); y = fmaf(f0[k].w, w[3], y);
      y = fmaf(f1[k].x, w[4], y); y = fmaf(f1[k].y, w[5], y);
      y = fmaf(f1[k].z, w[6], y); y = fmaf(f1[k].w, w[7], y);
      y = fmaf(f2[k].x, w[8], y); y = fmaf(f2[k].y, w[9], y);
      y = fmaf(f2[k].z, w[10], y); y = fmaf(f2[k].w, w[11], y);
      y += pa[k] + pb[k];
      if (act) {
        sum += y;
        ssq += y * y;
        y1[(size_t)(e + k) * 28 + c] = f2bf(y);  // 56B dense per edge
      }
    }
  }
  for (; e < e1; e++) {
    const int sI = src[e], dI = dst[e];
    const float pa = bf2f(Psrc[(size_t)(u32)sI * 32 + c]);
    const float pb = bf2f(Pdst[(size_t)(u32)dI * 32 + c]);
    const float4* e4 = (const float4*)(ef + (size_t)e * 12);
    float4 f0 = e4[0], f1 = e4[1], f2 = e4[2];
    float y = bias;
    y = fmaf(f0.x, w[0], y); y = fmaf(f0.y, w[1], y);
    y = fmaf(f0.z, w[2], y); y = fmaf(f0.w, w[3], y);
    y = fmaf(f1.x, w[4], y); y = fmaf(f1.y, w[5], y);
    y = fmaf(f1.z, w[6], y); y = fmaf(f1.w, w[7], y);
    y = fmaf(f2.x, w[8], y); y = fmaf(f2.y, w[9], y);
    y = fmaf(f2.z, w[10], y); y = fmaf(f2.w, w[11], y);
    y += pa + pb;
    if (act) {
      sum += y;
      ssq += y * y;
      y1[(size_t)e * 28 + c] = f2bf(y);
    }
  }

  // combine the wave's two half-groups (same channel c), block-reduce, atomics
  sum += __shfl_xor(sum, 32);
  ssq += __shfl_xor(ssq, 32);
  __shared__ float red[2][4][28];
  const int wave = tid >> 6;
  if (lane < 28) { red[0][wave][lane] = sum; red[1][wave][lane] = ssq; }
  __syncthreads();
  if (tid < 28) {
    atomicAdd(&stats[tid], red[0][0][tid] + red[0][1][tid] + red[0][2][tid] + red[0][3][tid]);
    atomicAdd(&stats[28 + tid], red[1][0][tid] + red[1][1][tid] + red[1][2][tid] + red[1][3][tid]);
  }
}

// K4: LDS-staged tiles over packed 56B rows. Block stages 256 rows (14 u32 each)
// coalesced into LDS (row stride 15 -> gcd(15,32)=1, 2-way max = free), then
// thread t computes edge T+t. BN1 coefs folded per-thread.
__global__ void __launch_bounds__(256) k4_l2(
    const u32* __restrict__ y1w, const float* __restrict__ stats,
    const float* __restrict__ g1, const float* __restrict__ be1,
    const float* __restrict__ W2, const float* __restrict__ b2,
    u16* __restrict__ y2, float* __restrict__ stats2, int E, float invE) {
  __shared__ u32 tile[256 * 15];
  float sc[28], sh[28];
#pragma unroll
  for (int cc = 0; cc < 28; cc++) {
    const float m = stats[cc] * invE;
    const float v = stats[28 + cc] * invE - m * m;
    const float s = g1[cc] * rsqrtf(v + BN_EPS);
    sc[cc] = s; sh[cc] = be1[cc] - m * s;
  }
  float as[8], aq[8];
#pragma unroll
  for (int o = 0; o < 8; o++) { as[o] = 0.f; aq[o] = 0.f; }
  const int tid = threadIdx.x;
  for (int T = blockIdx.x * 256; T < E; T += gridDim.x * 256) {
    int cnt = E - T; if (cnt > 256) cnt = 256;
    __syncthreads();
    const int total = cnt * 14;
    for (int i = tid; i < total; i += 256) {
      const int r = i / 14, j = i - r * 14;
      tile[r * 15 + j] = __builtin_nontemporal_load(&y1w[(size_t)T * 14 + i]);
    }
    __syncthreads();
    if (tid < cnt) {
      u32 uu[14];
#pragma unroll
      for (int i = 0; i < 14; i++) uu[i] = tile[tid * 15 + i];
      float acc[8];
#pragma unroll
      for (int o = 0; o < 8; o++) acc[o] = b2[o];
#pragma unroll
      for (int k = 0; k < 14; k++) {
        const float fe = __uint_as_float(uu[k] << 16);
        const float fo = __uint_as_float(uu[k] & 0xffff0000u);
        const float se = fmaxf(fmaf(fe, sc[2 * k], sh[2 * k]), 0.f);
        const float so = fmaxf(fmaf(fo, sc[2 * k + 1], sh[2 * k + 1]), 0.f);
#pragma unroll
        for (int o = 0; o < 8; o++) {
          acc[o] = fmaf(W2[o * 28 + 2 * k], se, acc[o]);      // uniform -> s_load
          acc[o] = fmaf(W2[o * 28 + 2 * k + 1], so, acc[o]);
        }
      }
      *(uint4*)(y2 + (size_t)(T + tid) * 8) =
          make_uint4(pack2(acc[0], acc[1]), pack2(acc[2], acc[3]),
                     pack2(acc[4], acc[5]), pack2(acc[6], acc[7]));
#pragma unroll
      for (int o = 0; o < 8; o++) { as[o] += acc[o]; aq[o] += acc[o] * acc[o]; }
    }
  }
#pragma unroll
  for (int o = 0; o < 8; o++) {
    for (int off = 32; off; off >>= 1) {
      as[o] += __shfl_down(as[o], off);
      aq[o] += __shfl_down(aq[o], off);
    }
  }
  __shared__ float redS[4][16];
  const int wave = tid >> 6, lane = tid & 63;
  if (lane == 0) {
#pragma unroll
    for (int o = 0; o < 8; o++) { redS[wave][o] = as[o]; redS[wave][8 + o] = aq[o]; }
  }
  __syncthreads();
  if (tid < 16) {
    atomicAdd(&stats2[tid], redS[0][tid] + redS[1][tid] + redS[2][tid] + redS[3][tid]);
  }
}

// K6: BN2 coefs per-thread, out = relu(BN2(y2)) @ W3.T + b3
__global__ void k6_l3(const u16* __restrict__ y2, const float* __restrict__ stats,
                      const float* __restrict__ g2, const float* __restrict__ be2,
                      const float* __restrict__ W3, const float* __restrict__ b3,
                      float* __restrict__ out, int E, float invE) {
  float sc[8], sh[8], w3[8];
#pragma unroll
  for (int o = 0; o < 8; o++) {
    const float m = stats[56 + o] * invE;
    const float v = stats[64 + o] * invE - m * m;
    const float s = g2[o] * rsqrtf(v + BN_EPS);
    sc[o] = s; sh[o] = be2[o] - m * s; w3[o] = W3[o];
  }
  const int e = blockIdx.x * blockDim.x + threadIdx.x;
  if (e >= E) return;
  const uint4 r = *(const uint4*)(y2 + (size_t)e * 8);
  u32 uu[4] = {r.x, r.y, r.z, r.w};
  float acc = b3[0];
#pragma unroll
  for (int k = 0; k < 4; k++) {
    const float fe = __uint_as_float(uu[k] << 16);
    const float fo = __uint_as_float(uu[k] & 0xffff0000u);
    acc = fmaf(w3[2 * k], fmaxf(fmaf(fe, sc[2 * k], sh[2 * k]), 0.f), acc);
    acc = fmaf(w3[2 * k + 1], fmaxf(fmaf(fo, sc[2 * k + 1], sh[2 * k + 1]), 0.f), acc);
  }
  out[e] = acc;
}

extern "C" void kernel_launch(void* const* d_in, const int* in_sizes, int n_in,
                              void* d_out, int out_size, void* d_ws, size_t ws_size,
                              hipStream_t stream) {
  const float* h   = (const float*)d_in[0];
  const float* ef  = (const float*)d_in[1];
  const int* src   = (const int*)d_in[2];
  const int* dst   = (const int*)d_in[3];
  const float* W1  = (const float*)d_in[4];
  const float* b1  = (const float*)d_in[5];
  const float* g1  = (const float*)d_in[6];
  const float* be1 = (const float*)d_in[7];
  const float* W2  = (const float*)d_in[8];
  const float* b2  = (const float*)d_in[9];
  const float* g2  = (const float*)d_in[10];
  const float* be2 = (const float*)d_in[11];
  const float* W3  = (const float*)d_in[12];
  const float* b3  = (const float*)d_in[13];
  float* out = (float*)d_out;

  const int N = in_sizes[0] / 128;
  const int E = in_sizes[2];
  const float invE = 1.0f / (float)E;

  char* ws = (char*)d_ws;
  float* stats = (float*)ws;                       // 72 floats
  u16* Psrc = (u16*)(ws + 1024);
  u16* Pdst = Psrc + (size_t)N * 32;
  u16* y1   = Pdst + (size_t)N * 32;               // E*28 packed
  u16* y2   = y1 + (size_t)E * 28;

  const int nodeBlocks = (N + 255) / 256;
  k1_proj<<<nodeBlocks * 2, 256, 0, stream>>>(h, W1, Psrc, Pdst, stats, N);

  const int K2B = 2048;                            // 16384 half-wave groups
  int epw = (E + K2B * 8 - 1) / (K2B * 8);
  epw = (epw + 7) & ~7;                            // multiple of 8 -> aligned int4
  k2_l1<<<K2B, 256, 0, stream>>>(Psrc, Pdst, ef, src, dst, W1, b1, y1, stats, E, epw);

  const int K4B = (E + 255) / 256;
  k4_l2<<<K4B, 256, 0, stream>>>((const u32*)y1, stats, g1, be1, W2, b2, y2,
                                 stats + 56, E, invE);
  k6_l3<<<(E + 255) / 256, 256, 0, stream>>>(y2, stats, g2, be2, W3, b3, out, E, invE);
}